// Round 7
// baseline (7252.097 us; speedup 1.0000x reference)
//
#include <hip/hip_runtime.h>
#include <hip/hip_bf16.h>
#include <cstdint>
#include <cstddef>

// Encoder: x[32,128] -> embed(E) -> biGRU(fw,bw) -> concat -> GRU m0 -> m1 -> top
// R7: cross-XCD h-exchange via 8B agent-scope relaxed atomics (SC1 -> IF
// coherence point). No per-step threadfences: no buffer_inv (xp stays warm in
// L2), no manual wbl2. Flag store stays RELEASE (waitcnt-ordered after h
// stores). Epilogue: 256 thr x (batch, 4 units), float4 xp loads, one 8B
// packed h store. gatesLDS padded to 33 to kill 4-way write conflicts.
//
// ws layout (float offsets):
//   XPA 0..6291456         fw/moving xp (4096x1536 f32)
//   XPB 6291456..12582912  bw xp; later: Y1@+0, Y2@+2097152, WTL@+4194304
//   YBI 12582912..16777216 bi concat y f32; early WT (fw,bw) aliases here
//   FLG 16777216 (2 int)  BAR 16777224 (128 int)  H 16777352 (32768 f)
//   END 16810120 f = 67.24 MB

typedef __hip_bfloat16 bf16;
typedef __attribute__((ext_vector_type(8))) short short8;   // 8 bf16
typedef __attribute__((ext_vector_type(4))) float f32x4;

#define T_SEQ 128
#define NB    32
#define UNITS 512
#define THREE_U 1536
#define GBLKS 16

#define OFF_XPA 0
#define OFF_XPB 6291456
#define OFF_YBI 12582912
#define OFF_FLG 16777216
#define OFF_BAR 16777224
#define OFF_H   16777352
#define OFF_END 16810120

__device__ __forceinline__ float sigf(float v) {
    return 1.0f / (1.0f + __expf(-v));
}

__global__ void detect_dtypes(const void* __restrict__ Uprobe,
                              const void* __restrict__ xprobe,
                              int* __restrict__ flags)
{
    if (threadIdx.x == 0) {
        const uint16_t* ub = (const uint16_t*)Uprobe;
        int big = 0;
        for (int i = 0; i < 64; ++i) {
            int e = (ub[i] >> 7) & 0xff;
            if (e >= 128) ++big;
        }
        flags[0] = (big >= 4) ? 1 : 0;   // 1: floats are f32
        const int* xi = (const int*)xprobe;
        int nzodd = 0;
        for (int i = 1; i < 256; i += 2) if (xi[i] != 0) ++nzodd;
        flags[1] = (nzodd < 4) ? 1 : 0;  // 1: ints are int64
    }
}

__device__ __forceinline__ int tok_at(const void* x, int idx, bool i64) {
    return i64 ? (int)((const long long*)x)[idx] : ((const int*)x)[idx];
}

// ---------------- W transpose: W[K][1536] -> WT[1536][K] bf16 ----------------
__global__ __launch_bounds__(256) void transpose_w(
    const void* __restrict__ W, uint16_t* __restrict__ WT, int K,
    const int* __restrict__ flags)
{
    const bool f32w = flags[0] != 0;
    __shared__ uint16_t tile[32][33];
    const int k0 = blockIdx.x * 32;
    const int n0 = blockIdx.y * 32;
    const int c = threadIdx.x & 31, r4 = threadIdx.x >> 5;
#pragma unroll
    for (int rr = 0; rr < 32; rr += 8) {
        int k = k0 + rr + r4;
        size_t off = (size_t)k * THREE_U + n0 + c;
        uint16_t v;
        if (f32w) v = __builtin_bit_cast(unsigned short, __float2bfloat16(((const float*)W)[off]));
        else      v = ((const uint16_t*)W)[off];
        tile[rr + r4][c] = v;
    }
    __syncthreads();
#pragma unroll
    for (int rr = 0; rr < 32; rr += 8) {
        int n = rr + r4;
        WT[(size_t)(n0 + n) * K + k0 + c] = tile[c][n];
    }
}

// ---------------- MFMA input-projection GEMM (split-bf16 A) ----------------
__global__ __launch_bounds__(256) void gemm_mfma(
    const float* __restrict__ Af, int lda,
    const void* __restrict__ xv, const void* __restrict__ E,
    const uint16_t* __restrict__ WT0, const void* __restrict__ b0, float* __restrict__ C0,
    const uint16_t* __restrict__ WT1, const void* __restrict__ b1, float* __restrict__ C1,
    int K, const int* __restrict__ flags)
{
    const bool f32w = flags[0] != 0;
    const bool i64  = flags[1] != 0;
    const uint16_t* WT = WT0; const void* bias = b0; float* C = C0;
    if (blockIdx.z == 1) { WT = WT1; bias = b1; C = C1; }

    __shared__ uint16_t AsHi[64][40];   // [m][k] stride 40
    __shared__ uint16_t AsLo[64][40];
    __shared__ uint16_t Ws[64][40];     // [n][k]

    const int tid = threadIdx.x;
    const int bn = blockIdx.x * 64, bm = blockIdx.y * 64;
    const int wave = tid >> 6, lane = tid & 63, quad = lane >> 4, l15 = lane & 15;
    const int wm = (wave & 1) * 32, wn = (wave >> 1) * 32;
    const int arow = tid >> 2;         // 0..63
    const int akoff = (tid & 3) * 8;   // 0,8,16,24

    f32x4 acc[2][2] = {};

    for (int k0 = 0; k0 < K; k0 += 32) {
        {
            const int mrow = bm + arow;
            float av[8];
            if (xv) {
                size_t tok = (size_t)tok_at(xv, mrow, i64);
                if (f32w) {
                    const float* p = (const float*)E + tok * (size_t)K + k0 + akoff;
#pragma unroll
                    for (int j = 0; j < 8; ++j) av[j] = p[j];
                } else {
                    const uint16_t* p = (const uint16_t*)E + tok * (size_t)K + k0 + akoff;
#pragma unroll
                    for (int j = 0; j < 8; ++j)
                        av[j] = __uint_as_float((unsigned)p[j] << 16);
                }
            } else {
                const float* p = Af + (size_t)mrow * lda + k0 + akoff;
#pragma unroll
                for (int j = 0; j < 8; ++j) av[j] = p[j];
            }
            short8 vh, vl;
#pragma unroll
            for (int j = 0; j < 8; ++j) {
                unsigned short hb = __builtin_bit_cast(unsigned short, __float2bfloat16(av[j]));
                float hi = __uint_as_float((unsigned)hb << 16);
                unsigned short lb = __builtin_bit_cast(unsigned short, __float2bfloat16(av[j] - hi));
                vh[j] = (short)hb; vl[j] = (short)lb;
            }
            *(short8*)&AsHi[arow][akoff] = vh;
            *(short8*)&AsLo[arow][akoff] = vl;
        }
        *(short8*)&Ws[arow][akoff] = *(const short8*)(WT + (size_t)(bn + arow) * K + k0 + akoff);
        __syncthreads();
#pragma unroll
        for (int i = 0; i < 2; ++i) {
            short8 ah = *(const short8*)&AsHi[wm + i*16 + l15][quad * 8];
            short8 al = *(const short8*)&AsLo[wm + i*16 + l15][quad * 8];
#pragma unroll
            for (int j = 0; j < 2; ++j) {
                short8 b = *(const short8*)&Ws[wn + j*16 + l15][quad * 8];
                acc[i][j] = __builtin_amdgcn_mfma_f32_16x16x32_bf16(ah, b, acc[i][j], 0, 0, 0);
                acc[i][j] = __builtin_amdgcn_mfma_f32_16x16x32_bf16(al, b, acc[i][j], 0, 0, 0);
            }
        }
        __syncthreads();
    }

#pragma unroll
    for (int i = 0; i < 2; ++i)
#pragma unroll
    for (int j = 0; j < 2; ++j) {
        int n = bn + wn + j*16 + l15;
        float bv = f32w ? ((const float*)bias)[n]
                        : __bfloat162float(((const bf16*)bias)[n]);
#pragma unroll
        for (int r = 0; r < 4; ++r) {
            int m = bm + wm + i*16 + quad*4 + r;
            C[(size_t)m * THREE_U + n] = acc[i][j][r] + bv;
        }
    }
}

// ---------------- weight-stationary GRU recurrence ----------------
// GBLKS blocks/group (x2 for biGRU), 384 thr. Block g owns units [g*32,+32);
// wave w: gate=w>>1, half=w&1, holds 512x16 U-slice as 16 B-frags.
// h exchange: bf16 double buffer, 8B AGENT-scope relaxed atomics (SC1 -> IF,
// coherent cross-XCD, no cache maintenance). Flags: release store + relaxed
// polls. y/out stores plain (consumed only by later kernels).
typedef union { unsigned long long d[2]; short8 v; } apack;

__global__ __launch_bounds__(384) void gru_mfma(
    const float* __restrict__ xp0, const void* __restrict__ U0, const void* __restrict__ b0full,
    const float* __restrict__ xp1, const void* __restrict__ U1, const void* __restrict__ b1full,
    const void* __restrict__ x,
    float* __restrict__ ybuf, int y_stride,
    void* __restrict__ outv,
    uint16_t* __restrict__ hbase,
    int* __restrict__ bar, int flag_base,
    const int* __restrict__ flags)
{
    const bool f32w = flags[0] != 0;
    const bool i64  = flags[1] != 0;

    int group = 0, gblk = blockIdx.x;
    const float* xp = xp0; const void* U = U0; const void* bfull = b0full;
    bool bwd = false; int coloff = 0;
    if (xp1 != nullptr) {
        group = blockIdx.x >> 4; gblk = blockIdx.x & 15;
        if (group == 1) { bwd = true; xp = xp1; U = U1; bfull = b1full; coloff = UNITS; }
    }
    int* flag = bar + flag_base + group * GBLKS;
    uint16_t* hpair = hbase + group * 2 * (NB * UNITS);

    const int tid  = threadIdx.x;
    const int wave = tid >> 6;
    const int lane = tid & 63;
    const int quad = lane >> 4;
    const int ncol = lane & 15;
    const int gate_w = wave >> 1;   // 0=z 1=r 2=hh
    const int hf     = wave & 1;

    __shared__ float gatesLDS[3][NB][33];   // padded: no 4-way write conflict
    __shared__ float hsLDS[NB][32];
    __shared__ float biasLDS[3][32];
    __shared__ int   maskLDS[NB];

    for (int p = tid; p < NB*32; p += 384) hsLDS[p >> 5][p & 31] = 0.f;
    if (tid < 96) {
        int g = tid >> 5, u = tid & 31;
        int idx = THREE_U + g*UNITS + gblk*32 + u;   // b_rec row
        biasLDS[g][u] = f32w ? ((const float*)bfull)[idx]
                             : __bfloat162float(((const bf16*)bfull)[idx]);
    }

    // Register-resident B-frags: B[k = kk*32+quad*8+j][n = ncol]
    short8 Bf[16];
    {
        const int col = gate_w*UNITS + gblk*32 + hf*16 + ncol;
#pragma unroll
        for (int kk = 0; kk < 16; ++kk) {
            short8 v;
#pragma unroll
            for (int j = 0; j < 8; ++j) {
                int k = kk*32 + quad*8 + j;
                unsigned short bits;
                if (f32w) {
                    bits = __builtin_bit_cast(unsigned short,
                        __float2bfloat16(((const float*)U)[(size_t)k*THREE_U + col]));
                } else {
                    bits = ((const uint16_t*)U)[(size_t)k*THREE_U + col];
                }
                v[j] = (short)bits;
            }
            Bf[kk] = v;
        }
    }

    // epilogue work split: 256 threads own (batch b, 4 units q*4..q*4+3)
    const int ep = tid;
    const int eb = ep >> 3, eq = (ep & 7) * 4;      // valid when ep < 256
    const int eug = gblk*32 + eq;

    __syncthreads();

    for (int ts = 0; ts < T_SEQ; ++ts) {
        const int t = bwd ? (T_SEQ-1-ts) : ts;
        const uint16_t* hc = hpair + (ts & 1) * (NB*UNITS);
        uint16_t* hnx      = hpair + ((ts+1) & 1) * (NB*UNITS);

        // (1) prefetch mask + xp (plain loads; L2 stays warm -- no invalidates)
        if (tid < NB) maskLDS[tid] = (tok_at(x, tid*T_SEQ + t, i64) != 0);
        f32x4 xz4 = {}, xr4 = {}, xh4 = {};
        if (ep < 256) {
            const float* xpt = xp + ((size_t)eb*T_SEQ + t)*THREE_U + eug;
            xz4 = *(const f32x4*)(xpt);
            xr4 = *(const f32x4*)(xpt + UNITS);
            xh4 = *(const f32x4*)(xpt + 2*UNITS);
        }

        // (2) rec = h[32,512] @ Uslice[512,16]; A-frags via agent atomics (IF)
        f32x4 acc0 = {0.f,0.f,0.f,0.f};
        f32x4 acc1 = {0.f,0.f,0.f,0.f};
        {
            const uint16_t* base0 = hc + (size_t)ncol*UNITS + quad*8;  // b 0..15
            const uint16_t* base1 = base0 + 16*UNITS;                   // b 16..31
#pragma unroll
            for (int kk = 0; kk < 16; ++kk) {
                const unsigned long long* p0 = (const unsigned long long*)(base0 + kk*32);
                const unsigned long long* p1 = (const unsigned long long*)(base1 + kk*32);
                apack a0, a1;
                a0.d[0] = __hip_atomic_load(p0,   __ATOMIC_RELAXED, __HIP_MEMORY_SCOPE_AGENT);
                a0.d[1] = __hip_atomic_load(p0+1, __ATOMIC_RELAXED, __HIP_MEMORY_SCOPE_AGENT);
                a1.d[0] = __hip_atomic_load(p1,   __ATOMIC_RELAXED, __HIP_MEMORY_SCOPE_AGENT);
                a1.d[1] = __hip_atomic_load(p1+1, __ATOMIC_RELAXED, __HIP_MEMORY_SCOPE_AGENT);
                acc0 = __builtin_amdgcn_mfma_f32_16x16x32_bf16(a0.v, Bf[kk], acc0, 0, 0, 0);
                acc1 = __builtin_amdgcn_mfma_f32_16x16x32_bf16(a1.v, Bf[kk], acc1, 0, 0, 0);
            }
        }
        // (3) gates -> LDS (C/D: col=lane&15, row=quad*4+reg)
        {
            const int u = hf*16 + ncol;
#pragma unroll
            for (int r = 0; r < 4; ++r) {
                gatesLDS[gate_w][quad*4 + r][u]      = acc0[r];
                gatesLDS[gate_w][16 + quad*4 + r][u] = acc1[r];
            }
        }
        __syncthreads();   // (4)

        // (5) epilogue: 4 units per thread
        if (ep < 256) {
            float hn4[4];
            unsigned long long hpack = 0ull;
            const int msk = maskLDS[eb];
#pragma unroll
            for (int j = 0; j < 4; ++j) {
                const int u = eq + j;
                const float hprev = hsLDS[eb][u];
                const float rz = gatesLDS[0][eb][u] + biasLDS[0][u];
                const float rr = gatesLDS[1][eb][u] + biasLDS[1][u];
                const float rh = gatesLDS[2][eb][u] + biasLDS[2][u];
                const float z = sigf(xz4[j] + rz);
                const float r = sigf(xr4[j] + rr);
                const float g = sigf(xh4[j] + r*rh);
                float hn = z*hprev + (1.f - z)*g;
                if (!msk) hn = hprev;
                hsLDS[eb][u] = hn;
                hn4[j] = hn;
                hpack |= (unsigned long long)
                    __builtin_bit_cast(unsigned short, __float2bfloat16(hn)) << (16*j);
            }
            // h exchange: single 8B agent-scope store (SC1 -> IF)
            __hip_atomic_store((unsigned long long*)(hnx + eb*UNITS + eug), hpack,
                               __ATOMIC_RELAXED, __HIP_MEMORY_SCOPE_AGENT);
            if (outv) {
                const size_t o = ((size_t)eb*T_SEQ + t)*UNITS + eug;
                if (f32w) {
                    *(f32x4*)((float*)outv + o) = *(f32x4*)hn4;
                    if (ts == T_SEQ-1)
                        *(f32x4*)((float*)outv + (size_t)NB*T_SEQ*UNITS + (size_t)eb*UNITS + eug)
                            = *(f32x4*)hn4;
                } else {
                    *((unsigned long long*)((uint16_t*)outv + o)) = hpack;
                    if (ts == T_SEQ-1)
                        *((unsigned long long*)((uint16_t*)outv
                            + (size_t)NB*T_SEQ*UNITS + (size_t)eb*UNITS + eug)) = hpack;
                }
            } else {
                *(f32x4*)(ybuf + ((size_t)eb*T_SEQ + t)*y_stride + coloff + eug)
                    = *(f32x4*)hn4;
            }
        }
        __syncthreads();   // (6) drains vmcnt: all h atomics complete at IF

        // (7) inter-block epoch barrier (no cache-maintenance fences)
        if (ts < T_SEQ-1) {
            const int target = ts + 1;
            if (tid == 0) {
                // RELEASE orders after the drained h stores; wbl2 it emits is
                // near-empty (h went SC1, y dirty lines are small)
                __hip_atomic_store(flag + gblk, target, __ATOMIC_RELEASE,
                                   __HIP_MEMORY_SCOPE_AGENT);
            }
            if (tid < GBLKS) {
                while (__hip_atomic_load(flag + tid, __ATOMIC_RELAXED,
                                         __HIP_MEMORY_SCOPE_AGENT) < target) {
                    __builtin_amdgcn_s_sleep(1);
                }
            }
            __atomic_signal_fence(__ATOMIC_ACQ_REL);  // compiler-only ordering
            __syncthreads();   // (8)
        }
    }
}

extern "C" void kernel_launch(void* const* d_in, const int* in_sizes, int n_in,
                              void* d_out, int out_size, void* d_ws, size_t ws_size,
                              hipStream_t stream) {
    const void* x     = d_in[0];
    const void* E     = d_in[2];
    const void* W_fw  = d_in[3];
    const void* U_fw  = d_in[4];
    const void* b_fw  = d_in[5];
    const void* W_bw  = d_in[6];
    const void* U_bw  = d_in[7];
    const void* b_bw  = d_in[8];
    const void* W_m0  = d_in[9];
    const void* U_m0  = d_in[10];
    const void* b_m0  = d_in[11];
    const void* W_m1  = d_in[12];
    const void* U_m1  = d_in[13];
    const void* b_m1  = d_in[14];
    const void* W_top = d_in[15];
    const void* U_top = d_in[16];
    const void* b_top = d_in[17];

    float* ws = (float*)d_ws;
    float*    XPA = ws + OFF_XPA;                    // 4096x1536 f32
    float*    XPB = ws + OFF_XPB;                    // 4096x1536 f32 (bw xp)
    float*    Y1  = XPB;                             // 4096x512 f32 (post-bi)
    float*    Y2  = XPB + 2097152;                   // 4096x512 f32
    uint16_t* WTL = (uint16_t*)(XPB + 4194304);      // late WT (<=1536x1024 bf16)
    float*    YBI = ws + OFF_YBI;                    // 4096x1024 f32 concat
    uint16_t* WTE = (uint16_t*)YBI;                  // early WT (fw,bw) alias
    uint16_t* WTEb = WTE + 786432;
    int*      flags = (int*)(ws + OFF_FLG);
    int*      bar   = (int*)(ws + OFF_BAR);
    uint16_t* hb    = (uint16_t*)(ws + OFF_H);

    hipMemsetAsync((char*)d_ws + (size_t)OFF_FLG*4, 0,
                   (size_t)(OFF_END - OFF_FLG)*4, stream);
    detect_dtypes<<<1, 64, 0, stream>>>(U_fw, x, flags);

    const dim3 b256(256);
    const dim3 gT512(16, 48), gT1024(32, 48);
    const dim3 gG2(24, 64, 2), gG1(24, 64, 1);

    // --- biGRU --- (early WT lives in YBI; dead before gru-bi writes YBI)
    transpose_w<<<gT512, b256, 0, stream>>>(W_fw, WTE, 512, flags);
    transpose_w<<<gT512, b256, 0, stream>>>(W_bw, WTEb, 512, flags);
    gemm_mfma<<<gG2, b256, 0, stream>>>(nullptr, 0, x, E,
                                        WTE, b_fw, XPA,
                                        WTEb, b_bw, XPB, 512, flags);
    gru_mfma<<<32, 384, 0, stream>>>(XPA, U_fw, b_fw,
                                     XPB, U_bw, b_bw,
                                     x, YBI, 1024, nullptr, hb, bar, 0, flags);
    // --- m0 (K=1024) ---
    transpose_w<<<gT1024, b256, 0, stream>>>(W_m0, WTL, 1024, flags);
    gemm_mfma<<<gG1, b256, 0, stream>>>(YBI, 1024, nullptr, nullptr,
                                        WTL, b_m0, XPA,
                                        nullptr, nullptr, nullptr, 1024, flags);
    hipMemsetAsync(hb, 0, 2*NB*UNITS*2, stream);
    gru_mfma<<<16, 384, 0, stream>>>(XPA, U_m0, b_m0,
                                     nullptr, nullptr, nullptr,
                                     x, Y1, 512, nullptr, hb, bar, 32, flags);
    // --- m1 ---
    transpose_w<<<gT512, b256, 0, stream>>>(W_m1, WTL, 512, flags);
    gemm_mfma<<<gG1, b256, 0, stream>>>(Y1, 512, nullptr, nullptr,
                                        WTL, b_m1, XPA,
                                        nullptr, nullptr, nullptr, 512, flags);
    hipMemsetAsync(hb, 0, 2*NB*UNITS*2, stream);
    gru_mfma<<<16, 384, 0, stream>>>(XPA, U_m1, b_m1,
                                     nullptr, nullptr, nullptr,
                                     x, Y2, 512, nullptr, hb, bar, 48, flags);
    // --- top ---
    transpose_w<<<gT512, b256, 0, stream>>>(W_top, WTL, 512, flags);
    gemm_mfma<<<gG1, b256, 0, stream>>>(Y2, 512, nullptr, nullptr,
                                        WTL, b_top, XPA,
                                        nullptr, nullptr, nullptr, 512, flags);
    hipMemsetAsync(hb, 0, 2*NB*UNITS*2, stream);
    gru_mfma<<<16, 384, 0, stream>>>(XPA, U_top, b_top,
                                     nullptr, nullptr, nullptr,
                                     x, nullptr, 0, d_out, hb, bar, 64, flags);
}

// Round 8
// 2494.691 us; speedup vs baseline: 2.9070x; 2.9070x over previous
//
#include <hip/hip_runtime.h>
#include <hip/hip_bf16.h>
#include <cstdint>
#include <cstddef>

// Encoder: x[32,128] -> embed(E) -> biGRU(fw,bw) -> concat -> GRU m0 -> m1 -> top
// R8: XCD-local GRU groups. 256 blocks launched; election (via HW_REG_XCC_ID +
// agent-scope per-XCD counters) picks 16 co-XCD workers per group; rest exit.
// Fast mode: h exchanged through the shared XCD L2 (plain stores + asm sc0
// loads staged to LDS) -- no wbl2 / no buffer_inv. Flags stay agent-scope (IF).
// Fallback mode (blocks not co-XCD): release-store(wbl2) + acquire-fence(inv),
// correct on any placement. ts=0 skips h reads (h==0), so no h memsets.
//
// ws layout (float offsets):
//   XPA 0..6291456         fw/moving xp (4096x1536 f32)
//   XPB 6291456..12582912  bw xp; later: Y1@+0, Y2@+2097152, WTL@+4194304
//   YBI 12582912..16777216 bi concat y f32; early WT (fw,bw) aliases here
//   FLG 16777216 (2 int)  BAR 16777224 (128 int)  EL 16777352 (16 int)
//   H   16777368 (2 groups x 2 slots x 16384 bf16 = 32768 f) END 16810136

typedef __hip_bfloat16 bf16;
typedef __attribute__((ext_vector_type(8))) short short8;      // 8 bf16
typedef __attribute__((ext_vector_type(4))) float f32x4;
typedef __attribute__((ext_vector_type(4))) unsigned int u32x4;

#define T_SEQ 128
#define NB    32
#define UNITS 512
#define THREE_U 1536
#define GBLKS 16

#define OFF_XPA 0
#define OFF_XPB 6291456
#define OFF_YBI 12582912
#define OFF_FLG 16777216
#define OFF_BAR 16777224
#define OFF_EL  16777352
#define OFF_H   16777368
#define OFF_END 16810136

// s_getreg imm for HW_REG_XCC_ID (id=20, offset 0, size 32)
#define XCC_GETREG_IMM 63508

__device__ __forceinline__ float sigf(float v) {
    return 1.0f / (1.0f + __expf(-v));
}

__global__ void detect_dtypes(const void* __restrict__ Uprobe,
                              const void* __restrict__ xprobe,
                              int* __restrict__ flags)
{
    if (threadIdx.x == 0) {
        const uint16_t* ub = (const uint16_t*)Uprobe;
        int big = 0;
        for (int i = 0; i < 64; ++i) {
            int e = (ub[i] >> 7) & 0xff;
            if (e >= 128) ++big;
        }
        flags[0] = (big >= 4) ? 1 : 0;   // 1: floats are f32
        const int* xi = (const int*)xprobe;
        int nzodd = 0;
        for (int i = 1; i < 256; i += 2) if (xi[i] != 0) ++nzodd;
        flags[1] = (nzodd < 4) ? 1 : 0;  // 1: ints are int64
    }
}

__device__ __forceinline__ int tok_at(const void* x, int idx, bool i64) {
    return i64 ? (int)((const long long*)x)[idx] : ((const int*)x)[idx];
}

// ---------------- W transpose: W[K][1536] -> WT[1536][K] bf16 ----------------
__global__ __launch_bounds__(256) void transpose_w(
    const void* __restrict__ W, uint16_t* __restrict__ WT, int K,
    const int* __restrict__ flags)
{
    const bool f32w = flags[0] != 0;
    __shared__ uint16_t tile[32][33];
    const int k0 = blockIdx.x * 32;
    const int n0 = blockIdx.y * 32;
    const int c = threadIdx.x & 31, r4 = threadIdx.x >> 5;
#pragma unroll
    for (int rr = 0; rr < 32; rr += 8) {
        int k = k0 + rr + r4;
        size_t off = (size_t)k * THREE_U + n0 + c;
        uint16_t v;
        if (f32w) v = __builtin_bit_cast(unsigned short, __float2bfloat16(((const float*)W)[off]));
        else      v = ((const uint16_t*)W)[off];
        tile[rr + r4][c] = v;
    }
    __syncthreads();
#pragma unroll
    for (int rr = 0; rr < 32; rr += 8) {
        int n = rr + r4;
        WT[(size_t)(n0 + n) * K + k0 + c] = tile[c][n];
    }
}

// ---------------- MFMA input-projection GEMM (split-bf16 A) ----------------
__global__ __launch_bounds__(256) void gemm_mfma(
    const float* __restrict__ Af, int lda,
    const void* __restrict__ xv, const void* __restrict__ E,
    const uint16_t* __restrict__ WT0, const void* __restrict__ b0, float* __restrict__ C0,
    const uint16_t* __restrict__ WT1, const void* __restrict__ b1, float* __restrict__ C1,
    int K, const int* __restrict__ flags)
{
    const bool f32w = flags[0] != 0;
    const bool i64  = flags[1] != 0;
    const uint16_t* WT = WT0; const void* bias = b0; float* C = C0;
    if (blockIdx.z == 1) { WT = WT1; bias = b1; C = C1; }

    __shared__ uint16_t AsHi[64][40];
    __shared__ uint16_t AsLo[64][40];
    __shared__ uint16_t Ws[64][40];

    const int tid = threadIdx.x;
    const int bn = blockIdx.x * 64, bm = blockIdx.y * 64;
    const int wave = tid >> 6, lane = tid & 63, quad = lane >> 4, l15 = lane & 15;
    const int wm = (wave & 1) * 32, wn = (wave >> 1) * 32;
    const int arow = tid >> 2;
    const int akoff = (tid & 3) * 8;

    f32x4 acc[2][2] = {};

    for (int k0 = 0; k0 < K; k0 += 32) {
        {
            const int mrow = bm + arow;
            float av[8];
            if (xv) {
                size_t tok = (size_t)tok_at(xv, mrow, i64);
                if (f32w) {
                    const float* p = (const float*)E + tok * (size_t)K + k0 + akoff;
#pragma unroll
                    for (int j = 0; j < 8; ++j) av[j] = p[j];
                } else {
                    const uint16_t* p = (const uint16_t*)E + tok * (size_t)K + k0 + akoff;
#pragma unroll
                    for (int j = 0; j < 8; ++j)
                        av[j] = __uint_as_float((unsigned)p[j] << 16);
                }
            } else {
                const float* p = Af + (size_t)mrow * lda + k0 + akoff;
#pragma unroll
                for (int j = 0; j < 8; ++j) av[j] = p[j];
            }
            short8 vh, vl;
#pragma unroll
            for (int j = 0; j < 8; ++j) {
                unsigned short hb = __builtin_bit_cast(unsigned short, __float2bfloat16(av[j]));
                float hi = __uint_as_float((unsigned)hb << 16);
                unsigned short lb = __builtin_bit_cast(unsigned short, __float2bfloat16(av[j] - hi));
                vh[j] = (short)hb; vl[j] = (short)lb;
            }
            *(short8*)&AsHi[arow][akoff] = vh;
            *(short8*)&AsLo[arow][akoff] = vl;
        }
        *(short8*)&Ws[arow][akoff] = *(const short8*)(WT + (size_t)(bn + arow) * K + k0 + akoff);
        __syncthreads();
#pragma unroll
        for (int i = 0; i < 2; ++i) {
            short8 ah = *(const short8*)&AsHi[wm + i*16 + l15][quad * 8];
            short8 al = *(const short8*)&AsLo[wm + i*16 + l15][quad * 8];
#pragma unroll
            for (int j = 0; j < 2; ++j) {
                short8 b = *(const short8*)&Ws[wn + j*16 + l15][quad * 8];
                acc[i][j] = __builtin_amdgcn_mfma_f32_16x16x32_bf16(ah, b, acc[i][j], 0, 0, 0);
                acc[i][j] = __builtin_amdgcn_mfma_f32_16x16x32_bf16(al, b, acc[i][j], 0, 0, 0);
            }
        }
        __syncthreads();
    }

#pragma unroll
    for (int i = 0; i < 2; ++i)
#pragma unroll
    for (int j = 0; j < 2; ++j) {
        int n = bn + wn + j*16 + l15;
        float bv = f32w ? ((const float*)bias)[n]
                        : __bfloat162float(((const bf16*)bias)[n]);
#pragma unroll
        for (int r = 0; r < 4; ++r) {
            int m = bm + wm + i*16 + quad*4 + r;
            C[(size_t)m * THREE_U + n] = acc[i][j][r] + bv;
        }
    }
}

// ---------------- weight-stationary GRU recurrence (XCD-local) ----------------
__global__ __launch_bounds__(384) void gru_mfma(
    const float* __restrict__ xp0, const void* __restrict__ U0, const void* __restrict__ b0full,
    const float* __restrict__ xp1, const void* __restrict__ U1, const void* __restrict__ b1full,
    const void* __restrict__ x,
    float* __restrict__ ybuf, int y_stride,
    void* __restrict__ outv,
    uint16_t* __restrict__ hbase,
    int* __restrict__ bar, int flag_base,
    int* __restrict__ el, int nGroups,
    const int* __restrict__ flags)
{
    const bool f32w = flags[0] != 0;
    const bool i64  = flags[1] != 0;
    const int tid = threadIdx.x;

    __shared__ int elA[4];   // mode, active, group, gblk

    // ---- election: all 256 blocks arrive; pick 16 co-XCD workers per group ----
    if (tid < 64) {
        const int lane = tid;
        int xcd = 0, rank = 0;
        if (lane == 0) {
            xcd = __builtin_amdgcn_s_getreg(XCC_GETREG_IMM) & 7;
            rank = __hip_atomic_fetch_add(&el[xcd], 1, __ATOMIC_RELAXED,
                                          __HIP_MEMORY_SCOPE_AGENT);
        }
        int total = 0;
        do {
            int c = (lane < 8) ? __hip_atomic_load(&el[lane], __ATOMIC_RELAXED,
                                                   __HIP_MEMORY_SCOPE_AGENT) : 0;
            c += __shfl_xor(c, 1);
            c += __shfl_xor(c, 2);
            c += __shfl_xor(c, 4);
            total = __shfl(c, 0);
            if (total < (int)gridDim.x) __builtin_amdgcn_s_sleep(8);
        } while (total < (int)gridDim.x);
        if (lane == 0) {
            int cnt[8];
            for (int i = 0; i < 8; ++i)
                cnt[i] = __hip_atomic_load(&el[i], __ATOMIC_RELAXED,
                                           __HIP_MEMORY_SCOPE_AGENT);
            int home0 = -1, home1 = -1;
            for (int i = 0; i < 8; ++i)
                if (cnt[i] >= 16) { if (home0 < 0) home0 = i; else if (home1 < 0) home1 = i; }
            const bool need2 = (nGroups == 2);
            const bool fb = (home0 < 0) || (need2 && home1 < 0 && cnt[home0] < 32);
            int mode = fb ? 0 : 1, active = 0, grp = 0, gb = 0;
            if (fb) {
                if ((int)blockIdx.x < nGroups * 16) {
                    active = 1; grp = (int)blockIdx.x >> 4; gb = (int)blockIdx.x & 15;
                }
            } else {
                if (xcd == home0 && rank < 16) { active = 1; grp = 0; gb = rank; }
                if (need2) {
                    if (home1 >= 0) {
                        if (xcd == home1 && rank < 16) { active = 1; grp = 1; gb = rank; }
                    } else if (xcd == home0 && rank >= 16 && rank < 32) {
                        active = 1; grp = 1; gb = rank - 16;
                    }
                }
            }
            elA[0] = mode; elA[1] = active; elA[2] = grp; elA[3] = gb;
        }
    }
    __syncthreads();
    if (!elA[1]) return;
    const int modeFast = elA[0];
    const int group    = elA[2];
    const int gblk     = elA[3];

    bool bwd = false; int coloff = 0;
    const float* xp = xp0; const void* U = U0; const void* bfull = b0full;
    if (group == 1) { bwd = true; xp = xp1; U = U1; bfull = b1full; coloff = UNITS; }
    int* flag = bar + flag_base + group * GBLKS;
    uint16_t* hpair = hbase + group * 2 * (NB * UNITS);

    const int wave = tid >> 6;
    const int lane = tid & 63;
    const int quad = lane >> 4;
    const int ncol = lane & 15;
    const int gate_w = wave >> 1;   // 0=z 1=r 2=hh
    const int hf     = wave & 1;

    __shared__ __align__(16) uint16_t hcLDS[NB * UNITS];   // 32 KB, XOR-swizzled rows
    __shared__ float gatesLDS[3][NB][33];
    __shared__ float hsLDS[NB][32];
    __shared__ float biasLDS[3][32];
    __shared__ int   maskLDS[NB];

    for (int p = tid; p < NB*32; p += 384) hsLDS[p >> 5][p & 31] = 0.f;
    if (tid < 96) {
        int g = tid >> 5, u = tid & 31;
        int idx = THREE_U + g*UNITS + gblk*32 + u;   // b_rec row
        biasLDS[g][u] = f32w ? ((const float*)bfull)[idx]
                             : __bfloat162float(((const bf16*)bfull)[idx]);
    }

    // Register-resident B-frags: B[k = kk*32+quad*8+j][n = ncol]
    short8 Bf[16];
    {
        const int col = gate_w*UNITS + gblk*32 + hf*16 + ncol;
#pragma unroll
        for (int kk = 0; kk < 16; ++kk) {
            short8 v;
#pragma unroll
            for (int j = 0; j < 8; ++j) {
                int k = kk*32 + quad*8 + j;
                unsigned short bits;
                if (f32w) {
                    bits = __builtin_bit_cast(unsigned short,
                        __float2bfloat16(((const float*)U)[(size_t)k*THREE_U + col]));
                } else {
                    bits = ((const uint16_t*)U)[(size_t)k*THREE_U + col];
                }
                v[j] = (short)bits;
            }
            Bf[kk] = v;
        }
    }

    const int eb = tid >> 3, eq = (tid & 7) * 4;   // epilogue owner (tid<256)
    const int eug = gblk*32 + eq;

    __syncthreads();

    for (int ts = 0; ts < T_SEQ; ++ts) {
        const int t = bwd ? (T_SEQ-1-ts) : ts;

        // (A) wait producers of step ts-1, stage h slot ts&1 into LDS
        if (ts > 0) {
            if (tid < GBLKS) {
                while (__hip_atomic_load(flag + tid, __ATOMIC_RELAXED,
                                         __HIP_MEMORY_SCOPE_AGENT) < ts)
                    __builtin_amdgcn_s_sleep(1);
            }
            __syncthreads();
            if (!modeFast) __builtin_amdgcn_fence(__ATOMIC_ACQUIRE, "agent");
            if (tid < 256) {
                const uint16_t* hsrc = hpair + (ts & 1) * (NB*UNITS) + (size_t)tid * 64;
                u32x4 r0, r1, r2, r3, r4, r5, r6, r7;
                asm volatile(
                    "global_load_dwordx4 %0, %8, off sc0\n\t"
                    "global_load_dwordx4 %1, %8, off offset:16 sc0\n\t"
                    "global_load_dwordx4 %2, %8, off offset:32 sc0\n\t"
                    "global_load_dwordx4 %3, %8, off offset:48 sc0\n\t"
                    "global_load_dwordx4 %4, %8, off offset:64 sc0\n\t"
                    "global_load_dwordx4 %5, %8, off offset:80 sc0\n\t"
                    "global_load_dwordx4 %6, %8, off offset:96 sc0\n\t"
                    "global_load_dwordx4 %7, %8, off offset:112 sc0\n\t"
                    "s_waitcnt vmcnt(0)"
                    : "=&v"(r0), "=&v"(r1), "=&v"(r2), "=&v"(r3),
                      "=&v"(r4), "=&v"(r5), "=&v"(r6), "=&v"(r7)
                    : "v"(hsrc)
                    : "memory");
                const int b = tid >> 3, jb = (tid & 7) * 8, bs = b & 7;
                u32x4* rowp = (u32x4*)(hcLDS + b * 512);
                rowp[(jb+0) ^ bs] = r0; rowp[(jb+1) ^ bs] = r1;
                rowp[(jb+2) ^ bs] = r2; rowp[(jb+3) ^ bs] = r3;
                rowp[(jb+4) ^ bs] = r4; rowp[(jb+5) ^ bs] = r5;
                rowp[(jb+6) ^ bs] = r6; rowp[(jb+7) ^ bs] = r7;
            }
            __syncthreads();
        }

        // (B) mask + xp prefetch
        if (tid < NB) maskLDS[tid] = (tok_at(x, tid*T_SEQ + t, i64) != 0);
        f32x4 xz4 = {}, xr4 = {}, xh4 = {};
        if (tid < 256) {
            const float* xpt = xp + ((size_t)eb*T_SEQ + t)*THREE_U + eug;
            xz4 = *(const f32x4*)(xpt);
            xr4 = *(const f32x4*)(xpt + UNITS);
            xh4 = *(const f32x4*)(xpt + 2*UNITS);
        }

        // (C) rec = h @ Uslice from LDS (h==0 at ts==0 -> acc stays 0)
        f32x4 acc0 = {0.f,0.f,0.f,0.f};
        f32x4 acc1 = {0.f,0.f,0.f,0.f};
        if (ts > 0) {
            const int bs = ncol & 7;   // same for rows ncol and 16+ncol
            const uint16_t* r0p = hcLDS + ncol * 512;
            const uint16_t* r1p = hcLDS + (16 + ncol) * 512;
#pragma unroll
            for (int kk = 0; kk < 16; ++kk) {
                const int jp = (quad + kk*4) ^ bs;
                short8 a0 = *(const short8*)(r0p + jp*8);
                short8 a1 = *(const short8*)(r1p + jp*8);
                acc0 = __builtin_amdgcn_mfma_f32_16x16x32_bf16(a0, Bf[kk], acc0, 0, 0, 0);
                acc1 = __builtin_amdgcn_mfma_f32_16x16x32_bf16(a1, Bf[kk], acc1, 0, 0, 0);
            }
        }
        // (D) gates -> LDS (C/D: col=lane&15, row=quad*4+reg)
        {
            const int u = hf*16 + ncol;
#pragma unroll
            for (int r = 0; r < 4; ++r) {
                gatesLDS[gate_w][quad*4 + r][u]      = acc0[r];
                gatesLDS[gate_w][16 + quad*4 + r][u] = acc1[r];
            }
        }
        __syncthreads();

        // (E) epilogue: compute h_new, store h (plain -> XCD L2)
        float hn4[4];
        unsigned long long hpack = 0ull;
        if (tid < 256) {
            const int msk = maskLDS[eb];
#pragma unroll
            for (int j = 0; j < 4; ++j) {
                const int u = eq + j;
                const float hprev = hsLDS[eb][u];
                const float rz = gatesLDS[0][eb][u] + biasLDS[0][u];
                const float rr = gatesLDS[1][eb][u] + biasLDS[1][u];
                const float rh = gatesLDS[2][eb][u] + biasLDS[2][u];
                const float z = sigf(xz4[j] + rz);
                const float r = sigf(xr4[j] + rr);
                const float g = sigf(xh4[j] + r*rh);
                float hn = z*hprev + (1.f - z)*g;
                if (!msk) hn = hprev;
                hsLDS[eb][u] = hn;
                hn4[j] = hn;
                hpack |= (unsigned long long)
                    __builtin_bit_cast(unsigned short, __float2bfloat16(hn)) << (16*j);
            }
            *(unsigned long long*)(hpair + ((ts+1) & 1)*(NB*UNITS) + eb*UNITS + eug) = hpack;
        }
        __syncthreads();   // drains h stores (vmcnt) across all waves

        // (F) publish flag; fast: relaxed (h already visible in shared L2);
        //     fb: release (wbl2 pushes h to memory before flag)
        if (ts < T_SEQ-1 && tid == 0) {
            if (modeFast)
                __hip_atomic_store(flag + gblk, ts+1, __ATOMIC_RELAXED,
                                   __HIP_MEMORY_SCOPE_AGENT);
            else
                __hip_atomic_store(flag + gblk, ts+1, __ATOMIC_RELEASE,
                                   __HIP_MEMORY_SCOPE_AGENT);
        }

        // (G) y/out stores -- off the critical path, overlap next poll
        if (tid < 256) {
            if (outv) {
                const size_t o = ((size_t)eb*T_SEQ + t)*UNITS + eug;
                if (f32w) {
                    *(f32x4*)((float*)outv + o) = *(f32x4*)hn4;
                    if (ts == T_SEQ-1)
                        *(f32x4*)((float*)outv + (size_t)NB*T_SEQ*UNITS
                                  + (size_t)eb*UNITS + eug) = *(f32x4*)hn4;
                } else {
                    *(unsigned long long*)((uint16_t*)outv + o) = hpack;
                    if (ts == T_SEQ-1)
                        *(unsigned long long*)((uint16_t*)outv
                            + (size_t)NB*T_SEQ*UNITS + (size_t)eb*UNITS + eug) = hpack;
                }
            } else {
                *(f32x4*)(ybuf + ((size_t)eb*T_SEQ + t)*y_stride + coloff + eug)
                    = *(f32x4*)hn4;
            }
        }
    }
}

extern "C" void kernel_launch(void* const* d_in, const int* in_sizes, int n_in,
                              void* d_out, int out_size, void* d_ws, size_t ws_size,
                              hipStream_t stream) {
    const void* x     = d_in[0];
    const void* E     = d_in[2];
    const void* W_fw  = d_in[3];
    const void* U_fw  = d_in[4];
    const void* b_fw  = d_in[5];
    const void* W_bw  = d_in[6];
    const void* U_bw  = d_in[7];
    const void* b_bw  = d_in[8];
    const void* W_m0  = d_in[9];
    const void* U_m0  = d_in[10];
    const void* b_m0  = d_in[11];
    const void* W_m1  = d_in[12];
    const void* U_m1  = d_in[13];
    const void* b_m1  = d_in[14];
    const void* W_top = d_in[15];
    const void* U_top = d_in[16];
    const void* b_top = d_in[17];

    float* ws = (float*)d_ws;
    float*    XPA = ws + OFF_XPA;
    float*    XPB = ws + OFF_XPB;
    float*    Y1  = XPB;
    float*    Y2  = XPB + 2097152;
    uint16_t* WTL = (uint16_t*)(XPB + 4194304);
    float*    YBI = ws + OFF_YBI;
    uint16_t* WTE = (uint16_t*)YBI;
    uint16_t* WTEb = WTE + 786432;
    int*      flags = (int*)(ws + OFF_FLG);
    int*      bar   = (int*)(ws + OFF_BAR);
    int*      el    = (int*)(ws + OFF_EL);
    uint16_t* hb    = (uint16_t*)(ws + OFF_H);

    // zero flags + barrier epochs + election counters
    hipMemsetAsync((char*)d_ws + (size_t)OFF_FLG*4, 0,
                   (size_t)(OFF_H - OFF_FLG)*4, stream);
    detect_dtypes<<<1, 64, 0, stream>>>(U_fw, x, flags);

    const dim3 b256(256);
    const dim3 gT512(16, 48), gT1024(32, 48);
    const dim3 gG2(24, 64, 2), gG1(24, 64, 1);

    // --- biGRU ---
    transpose_w<<<gT512, b256, 0, stream>>>(W_fw, WTE, 512, flags);
    transpose_w<<<gT512, b256, 0, stream>>>(W_bw, WTEb, 512, flags);
    gemm_mfma<<<gG2, b256, 0, stream>>>(nullptr, 0, x, E,
                                        WTE, b_fw, XPA,
                                        WTEb, b_bw, XPB, 512, flags);
    gru_mfma<<<256, 384, 0, stream>>>(XPA, U_fw, b_fw,
                                      XPB, U_bw, b_bw,
                                      x, YBI, 1024, nullptr, hb, bar, 0,
                                      el, 2, flags);
    // --- m0 (K=1024) ---
    transpose_w<<<gT1024, b256, 0, stream>>>(W_m0, WTL, 1024, flags);
    gemm_mfma<<<gG1, b256, 0, stream>>>(YBI, 1024, nullptr, nullptr,
                                        WTL, b_m0, XPA,
                                        nullptr, nullptr, nullptr, 1024, flags);
    hipMemsetAsync(el, 0, 64, stream);
    gru_mfma<<<256, 384, 0, stream>>>(XPA, U_m0, b_m0,
                                      nullptr, nullptr, nullptr,
                                      x, Y1, 512, nullptr, hb, bar, 32,
                                      el, 1, flags);
    // --- m1 ---
    transpose_w<<<gT512, b256, 0, stream>>>(W_m1, WTL, 512, flags);
    gemm_mfma<<<gG1, b256, 0, stream>>>(Y1, 512, nullptr, nullptr,
                                        WTL, b_m1, XPA,
                                        nullptr, nullptr, nullptr, 512, flags);
    hipMemsetAsync(el, 0, 64, stream);
    gru_mfma<<<256, 384, 0, stream>>>(XPA, U_m1, b_m1,
                                      nullptr, nullptr, nullptr,
                                      x, Y2, 512, nullptr, hb, bar, 48,
                                      el, 1, flags);
    // --- top ---
    transpose_w<<<gT512, b256, 0, stream>>>(W_top, WTL, 512, flags);
    gemm_mfma<<<gG1, b256, 0, stream>>>(Y2, 512, nullptr, nullptr,
                                        WTL, b_top, XPA,
                                        nullptr, nullptr, nullptr, 512, flags);
    hipMemsetAsync(el, 0, 64, stream);
    gru_mfma<<<256, 384, 0, stream>>>(XPA, U_top, b_top,
                                      nullptr, nullptr, nullptr,
                                      x, nullptr, 0, d_out, hb, bar, 64,
                                      el, 1, flags);
}

// Round 9
// 2351.026 us; speedup vs baseline: 3.0847x; 1.0611x over previous
//
#include <hip/hip_runtime.h>
#include <hip/hip_bf16.h>
#include <cstdint>
#include <cstddef>

// Encoder: x[32,128] -> embed(E) -> biGRU(fw,bw) -> concat -> GRU m0 -> m1 -> top
// R9 (on R8's XCD-local structure):
//  - hcLDS staged in MFMA A-frag order: chunk c = half*1024+(kk*4+quad)*16+ncol.
//    Staging writes and frag reads are both lane-stride-1 -> near-zero LDS
//    bank conflicts (R8's XOR swizzle had 8-way write conflicts: 1.08e7/disp).
//  - Epoch flags spread to 64B stride: stores hit 16 distinct IF lines
//    (parallel), poll is one 16-lane instruction (parallel loads).
//  - xp/mask loads hoisted before the poll (latency hidden behind wait).
//
// ws layout (float offsets):
//   XPA 0..6291456         fw/moving xp (4096x1536 f32)
//   XPB 6291456..12582912  bw xp; later: Y1@+0, Y2@+2097152, WTL@+4194304
//   YBI 12582912..16777216 bi concat y f32; early WT (fw,bw) aliases here
//   FLG 16777216 (2 int)  BAR 16777224 (1280 int: 5 slots x 16 flags x 16 ints)
//   EL  16778504 (16 int)  H 16778520 (32768 f)  END 16811288 (67.25 MB)

typedef __hip_bfloat16 bf16;
typedef __attribute__((ext_vector_type(8))) short short8;      // 8 bf16
typedef __attribute__((ext_vector_type(4))) float f32x4;
typedef __attribute__((ext_vector_type(4))) unsigned int u32x4;

#define T_SEQ 128
#define NB    32
#define UNITS 512
#define THREE_U 1536
#define GBLKS 16
#define FLAG_STRIDE 16              // ints per flag (64B line each)

#define OFF_XPA 0
#define OFF_XPB 6291456
#define OFF_YBI 12582912
#define OFF_FLG 16777216
#define OFF_BAR 16777224
#define OFF_EL  16778504
#define OFF_H   16778520
#define OFF_END 16811288

// s_getreg imm for HW_REG_XCC_ID (id=20, offset 0, size 32)
#define XCC_GETREG_IMM 63508

__device__ __forceinline__ float sigf(float v) {
    return 1.0f / (1.0f + __expf(-v));
}

__global__ void detect_dtypes(const void* __restrict__ Uprobe,
                              const void* __restrict__ xprobe,
                              int* __restrict__ flags)
{
    if (threadIdx.x == 0) {
        const uint16_t* ub = (const uint16_t*)Uprobe;
        int big = 0;
        for (int i = 0; i < 64; ++i) {
            int e = (ub[i] >> 7) & 0xff;
            if (e >= 128) ++big;
        }
        flags[0] = (big >= 4) ? 1 : 0;   // 1: floats are f32
        const int* xi = (const int*)xprobe;
        int nzodd = 0;
        for (int i = 1; i < 256; i += 2) if (xi[i] != 0) ++nzodd;
        flags[1] = (nzodd < 4) ? 1 : 0;  // 1: ints are int64
    }
}

__device__ __forceinline__ int tok_at(const void* x, int idx, bool i64) {
    return i64 ? (int)((const long long*)x)[idx] : ((const int*)x)[idx];
}

// ---------------- W transpose: W[K][1536] -> WT[1536][K] bf16 ----------------
__global__ __launch_bounds__(256) void transpose_w(
    const void* __restrict__ W, uint16_t* __restrict__ WT, int K,
    const int* __restrict__ flags)
{
    const bool f32w = flags[0] != 0;
    __shared__ uint16_t tile[32][33];
    const int k0 = blockIdx.x * 32;
    const int n0 = blockIdx.y * 32;
    const int c = threadIdx.x & 31, r4 = threadIdx.x >> 5;
#pragma unroll
    for (int rr = 0; rr < 32; rr += 8) {
        int k = k0 + rr + r4;
        size_t off = (size_t)k * THREE_U + n0 + c;
        uint16_t v;
        if (f32w) v = __builtin_bit_cast(unsigned short, __float2bfloat16(((const float*)W)[off]));
        else      v = ((const uint16_t*)W)[off];
        tile[rr + r4][c] = v;
    }
    __syncthreads();
#pragma unroll
    for (int rr = 0; rr < 32; rr += 8) {
        int n = rr + r4;
        WT[(size_t)(n0 + n) * K + k0 + c] = tile[c][n];
    }
}

// ---------------- MFMA input-projection GEMM (split-bf16 A) ----------------
__global__ __launch_bounds__(256) void gemm_mfma(
    const float* __restrict__ Af, int lda,
    const void* __restrict__ xv, const void* __restrict__ E,
    const uint16_t* __restrict__ WT0, const void* __restrict__ b0, float* __restrict__ C0,
    const uint16_t* __restrict__ WT1, const void* __restrict__ b1, float* __restrict__ C1,
    int K, const int* __restrict__ flags)
{
    const bool f32w = flags[0] != 0;
    const bool i64  = flags[1] != 0;
    const uint16_t* WT = WT0; const void* bias = b0; float* C = C0;
    if (blockIdx.z == 1) { WT = WT1; bias = b1; C = C1; }

    __shared__ uint16_t AsHi[64][40];
    __shared__ uint16_t AsLo[64][40];
    __shared__ uint16_t Ws[64][40];

    const int tid = threadIdx.x;
    const int bn = blockIdx.x * 64, bm = blockIdx.y * 64;
    const int wave = tid >> 6, lane = tid & 63, quad = lane >> 4, l15 = lane & 15;
    const int wm = (wave & 1) * 32, wn = (wave >> 1) * 32;
    const int arow = tid >> 2;
    const int akoff = (tid & 3) * 8;

    f32x4 acc[2][2] = {};

    for (int k0 = 0; k0 < K; k0 += 32) {
        {
            const int mrow = bm + arow;
            float av[8];
            if (xv) {
                size_t tok = (size_t)tok_at(xv, mrow, i64);
                if (f32w) {
                    const float* p = (const float*)E + tok * (size_t)K + k0 + akoff;
#pragma unroll
                    for (int j = 0; j < 8; ++j) av[j] = p[j];
                } else {
                    const uint16_t* p = (const uint16_t*)E + tok * (size_t)K + k0 + akoff;
#pragma unroll
                    for (int j = 0; j < 8; ++j)
                        av[j] = __uint_as_float((unsigned)p[j] << 16);
                }
            } else {
                const float* p = Af + (size_t)mrow * lda + k0 + akoff;
#pragma unroll
                for (int j = 0; j < 8; ++j) av[j] = p[j];
            }
            short8 vh, vl;
#pragma unroll
            for (int j = 0; j < 8; ++j) {
                unsigned short hb = __builtin_bit_cast(unsigned short, __float2bfloat16(av[j]));
                float hi = __uint_as_float((unsigned)hb << 16);
                unsigned short lb = __builtin_bit_cast(unsigned short, __float2bfloat16(av[j] - hi));
                vh[j] = (short)hb; vl[j] = (short)lb;
            }
            *(short8*)&AsHi[arow][akoff] = vh;
            *(short8*)&AsLo[arow][akoff] = vl;
        }
        *(short8*)&Ws[arow][akoff] = *(const short8*)(WT + (size_t)(bn + arow) * K + k0 + akoff);
        __syncthreads();
#pragma unroll
        for (int i = 0; i < 2; ++i) {
            short8 ah = *(const short8*)&AsHi[wm + i*16 + l15][quad * 8];
            short8 al = *(const short8*)&AsLo[wm + i*16 + l15][quad * 8];
#pragma unroll
            for (int j = 0; j < 2; ++j) {
                short8 b = *(const short8*)&Ws[wn + j*16 + l15][quad * 8];
                acc[i][j] = __builtin_amdgcn_mfma_f32_16x16x32_bf16(ah, b, acc[i][j], 0, 0, 0);
                acc[i][j] = __builtin_amdgcn_mfma_f32_16x16x32_bf16(al, b, acc[i][j], 0, 0, 0);
            }
        }
        __syncthreads();
    }

#pragma unroll
    for (int i = 0; i < 2; ++i)
#pragma unroll
    for (int j = 0; j < 2; ++j) {
        int n = bn + wn + j*16 + l15;
        float bv = f32w ? ((const float*)bias)[n]
                        : __bfloat162float(((const bf16*)bias)[n]);
#pragma unroll
        for (int r = 0; r < 4; ++r) {
            int m = bm + wm + i*16 + quad*4 + r;
            C[(size_t)m * THREE_U + n] = acc[i][j][r] + bv;
        }
    }
}

// ---------------- weight-stationary GRU recurrence (XCD-local) ----------------
__global__ __launch_bounds__(384) void gru_mfma(
    const float* __restrict__ xp0, const void* __restrict__ U0, const void* __restrict__ b0full,
    const float* __restrict__ xp1, const void* __restrict__ U1, const void* __restrict__ b1full,
    const void* __restrict__ x,
    float* __restrict__ ybuf, int y_stride,
    void* __restrict__ outv,
    uint16_t* __restrict__ hbase,
    int* __restrict__ bar, int fbBase,
    int* __restrict__ el, int nGroups,
    const int* __restrict__ flags)
{
    const bool f32w = flags[0] != 0;
    const bool i64  = flags[1] != 0;
    const int tid = threadIdx.x;

    __shared__ int elA[4];   // mode, active, group, gblk

    // ---- election: all 256 blocks arrive; pick 16 co-XCD workers per group ----
    if (tid < 64) {
        const int lane = tid;
        int xcd = 0, rank = 0;
        if (lane == 0) {
            xcd = __builtin_amdgcn_s_getreg(XCC_GETREG_IMM) & 7;
            rank = __hip_atomic_fetch_add(&el[xcd], 1, __ATOMIC_RELAXED,
                                          __HIP_MEMORY_SCOPE_AGENT);
        }
        int total = 0;
        do {
            int c = (lane < 8) ? __hip_atomic_load(&el[lane], __ATOMIC_RELAXED,
                                                   __HIP_MEMORY_SCOPE_AGENT) : 0;
            c += __shfl_xor(c, 1);
            c += __shfl_xor(c, 2);
            c += __shfl_xor(c, 4);
            total = __shfl(c, 0);
            if (total < (int)gridDim.x) __builtin_amdgcn_s_sleep(8);
        } while (total < (int)gridDim.x);
        if (lane == 0) {
            int cnt[8];
            for (int i = 0; i < 8; ++i)
                cnt[i] = __hip_atomic_load(&el[i], __ATOMIC_RELAXED,
                                           __HIP_MEMORY_SCOPE_AGENT);
            int home0 = -1, home1 = -1;
            for (int i = 0; i < 8; ++i)
                if (cnt[i] >= 16) { if (home0 < 0) home0 = i; else if (home1 < 0) home1 = i; }
            const bool need2 = (nGroups == 2);
            const bool fb = (home0 < 0) || (need2 && home1 < 0 && cnt[home0] < 32);
            int mode = fb ? 0 : 1, active = 0, grp = 0, gb = 0;
            if (fb) {
                if ((int)blockIdx.x < nGroups * 16) {
                    active = 1; grp = (int)blockIdx.x >> 4; gb = (int)blockIdx.x & 15;
                }
            } else {
                if (xcd == home0 && rank < 16) { active = 1; grp = 0; gb = rank; }
                if (need2) {
                    if (home1 >= 0) {
                        if (xcd == home1 && rank < 16) { active = 1; grp = 1; gb = rank; }
                    } else if (xcd == home0 && rank >= 16 && rank < 32) {
                        active = 1; grp = 1; gb = rank - 16;
                    }
                }
            }
            elA[0] = mode; elA[1] = active; elA[2] = grp; elA[3] = gb;
        }
    }
    __syncthreads();
    if (!elA[1]) return;
    const int modeFast = elA[0];
    const int group    = elA[2];
    const int gblk     = elA[3];

    bool bwd = false; int coloff = 0;
    const float* xp = xp0; const void* U = U0; const void* bfull = b0full;
    if (group == 1) { bwd = true; xp = xp1; U = U1; bfull = b1full; coloff = UNITS; }
    int* flagArr = bar + (fbBase + group) * (GBLKS * FLAG_STRIDE);
    uint16_t* hpair = hbase + group * 2 * (NB * UNITS);

    const int wave = tid >> 6;
    const int lane = tid & 63;
    const int quad = lane >> 4;
    const int ncol = lane & 15;
    const int gate_w = wave >> 1;   // 0=z 1=r 2=hh
    const int hf     = wave & 1;

    // frag-ordered h cache: chunk c(16B) = half*1024 + (kk*4+quad)*16 + ncol
    __shared__ __align__(16) uint16_t hcLDS[NB * UNITS];   // 32 KB
    __shared__ float gatesLDS[3][NB][33];
    __shared__ float hsLDS[NB][32];
    __shared__ float biasLDS[3][32];
    __shared__ int   maskLDS[NB];

    for (int p = tid; p < NB*32; p += 384) hsLDS[p >> 5][p & 31] = 0.f;
    if (tid < 96) {
        int g = tid >> 5, u = tid & 31;
        int idx = THREE_U + g*UNITS + gblk*32 + u;   // b_rec row
        biasLDS[g][u] = f32w ? ((const float*)bfull)[idx]
                             : __bfloat162float(((const bf16*)bfull)[idx]);
    }

    // Register-resident B-frags: B[k = kk*32+quad*8+j][n = ncol]
    short8 Bf[16];
    {
        const int col = gate_w*UNITS + gblk*32 + hf*16 + ncol;
#pragma unroll
        for (int kk = 0; kk < 16; ++kk) {
            short8 v;
#pragma unroll
            for (int j = 0; j < 8; ++j) {
                int k = kk*32 + quad*8 + j;
                unsigned short bits;
                if (f32w) {
                    bits = __builtin_bit_cast(unsigned short,
                        __float2bfloat16(((const float*)U)[(size_t)k*THREE_U + col]));
                } else {
                    bits = ((const uint16_t*)U)[(size_t)k*THREE_U + col];
                }
                v[j] = (short)bits;
            }
            Bf[kk] = v;
        }
    }

    const int eb = tid >> 3, eq = (tid & 7) * 4;   // epilogue owner (tid<256)
    const int eug = gblk*32 + eq;

    __syncthreads();

    for (int ts = 0; ts < T_SEQ; ++ts) {
        const int t = bwd ? (T_SEQ-1-ts) : ts;

        // (B) xp + mask loads FIRST -- latency overlaps the poll below
        if (tid < NB) maskLDS[tid] = (tok_at(x, tid*T_SEQ + t, i64) != 0);
        f32x4 xz4 = {}, xr4 = {}, xh4 = {};
        if (tid < 256) {
            const float* xpt = xp + ((size_t)eb*T_SEQ + t)*THREE_U + eug;
            xz4 = *(const f32x4*)(xpt);
            xr4 = *(const f32x4*)(xpt + UNITS);
            xh4 = *(const f32x4*)(xpt + 2*UNITS);
        }

        // (A) wait producers of step ts-1; stage h slot ts&1 into frag-order LDS
        if (ts > 0) {
            if (tid < GBLKS) {
                while (__hip_atomic_load(flagArr + tid*FLAG_STRIDE, __ATOMIC_RELAXED,
                                         __HIP_MEMORY_SCOPE_AGENT) < ts)
                    __builtin_amdgcn_s_sleep(1);
            }
            __syncthreads();
            if (!modeFast) __builtin_amdgcn_fence(__ATOMIC_ACQUIRE, "agent");
            if (tid < 256) {
                const uint16_t* hq = hpair + (ts & 1) * (NB*UNITS);
                u32x4 r[8];
#pragma unroll
                for (int i = 0; i < 8; ++i) {
                    const int c = tid + i*256;
                    const int b = ((c >> 10) << 4) | (c & 15);
                    const int qk = (c >> 4) & 63;
                    const uint16_t* src = hq + b*512 + qk*8;
                    asm volatile("global_load_dwordx4 %0, %1, off sc0"
                                 : "=v"(r[i]) : "v"(src) : "memory");
                }
                asm volatile("s_waitcnt vmcnt(0)"
                             : "+v"(r[0]), "+v"(r[1]), "+v"(r[2]), "+v"(r[3]),
                               "+v"(r[4]), "+v"(r[5]), "+v"(r[6]), "+v"(r[7])
                             :: "memory");
#pragma unroll
                for (int i = 0; i < 8; ++i)
                    *(u32x4*)(hcLDS + (size_t)(tid + i*256) * 8) = r[i];
            }
            __syncthreads();
        }

        // (C) rec = h @ Uslice from frag-ordered LDS (h==0 at ts==0)
        f32x4 acc0 = {0.f,0.f,0.f,0.f};
        f32x4 acc1 = {0.f,0.f,0.f,0.f};
        if (ts > 0) {
            const uint16_t* fb0 = hcLDS + (quad*16 + ncol)*8;
#pragma unroll
            for (int kk = 0; kk < 16; ++kk) {
                short8 a0 = *(const short8*)(fb0 + kk*512);
                short8 a1 = *(const short8*)(fb0 + 8192 + kk*512);
                acc0 = __builtin_amdgcn_mfma_f32_16x16x32_bf16(a0, Bf[kk], acc0, 0, 0, 0);
                acc1 = __builtin_amdgcn_mfma_f32_16x16x32_bf16(a1, Bf[kk], acc1, 0, 0, 0);
            }
        }
        // (D) gates -> LDS (C/D: col=lane&15, row=quad*4+reg)
        {
            const int u = hf*16 + ncol;
#pragma unroll
            for (int r = 0; r < 4; ++r) {
                gatesLDS[gate_w][quad*4 + r][u]      = acc0[r];
                gatesLDS[gate_w][16 + quad*4 + r][u] = acc1[r];
            }
        }
        __syncthreads();

        // (E) epilogue: compute h_new, store h (plain -> shared XCD L2)
        float hn4[4];
        unsigned long long hpack = 0ull;
        if (tid < 256) {
            const int msk = maskLDS[eb];
#pragma unroll
            for (int j = 0; j < 4; ++j) {
                const int u = eq + j;
                const float hprev = hsLDS[eb][u];
                const float rz = gatesLDS[0][eb][u] + biasLDS[0][u];
                const float rr = gatesLDS[1][eb][u] + biasLDS[1][u];
                const float rh = gatesLDS[2][eb][u] + biasLDS[2][u];
                const float z = sigf(xz4[j] + rz);
                const float r = sigf(xr4[j] + rr);
                const float g = sigf(xh4[j] + r*rh);
                float hn = z*hprev + (1.f - z)*g;
                if (!msk) hn = hprev;
                hsLDS[eb][u] = hn;
                hn4[j] = hn;
                hpack |= (unsigned long long)
                    __builtin_bit_cast(unsigned short, __float2bfloat16(hn)) << (16*j);
            }
            *(unsigned long long*)(hpair + ((ts+1) & 1)*(NB*UNITS) + eb*UNITS + eug) = hpack;
        }
        __syncthreads();   // drains h stores (vmcnt) across all waves

        // (F) publish flag; fast: relaxed (h visible in shared L2);
        //     fb: release (wbl2 pushes h to memory before flag)
        if (ts < T_SEQ-1 && tid == 0) {
            if (modeFast)
                __hip_atomic_store(flagArr + gblk*FLAG_STRIDE, ts+1, __ATOMIC_RELAXED,
                                   __HIP_MEMORY_SCOPE_AGENT);
            else
                __hip_atomic_store(flagArr + gblk*FLAG_STRIDE, ts+1, __ATOMIC_RELEASE,
                                   __HIP_MEMORY_SCOPE_AGENT);
        }

        // (G) y/out stores -- off the critical path, overlap next poll
        if (tid < 256) {
            if (outv) {
                const size_t o = ((size_t)eb*T_SEQ + t)*UNITS + eug;
                if (f32w) {
                    *(f32x4*)((float*)outv + o) = *(f32x4*)hn4;
                    if (ts == T_SEQ-1)
                        *(f32x4*)((float*)outv + (size_t)NB*T_SEQ*UNITS
                                  + (size_t)eb*UNITS + eug) = *(f32x4*)hn4;
                } else {
                    *(unsigned long long*)((uint16_t*)outv + o) = hpack;
                    if (ts == T_SEQ-1)
                        *(unsigned long long*)((uint16_t*)outv
                            + (size_t)NB*T_SEQ*UNITS + (size_t)eb*UNITS + eug) = hpack;
                }
            } else {
                *(f32x4*)(ybuf + ((size_t)eb*T_SEQ + t)*y_stride + coloff + eug)
                    = *(f32x4*)hn4;
            }
        }
    }
}

extern "C" void kernel_launch(void* const* d_in, const int* in_sizes, int n_in,
                              void* d_out, int out_size, void* d_ws, size_t ws_size,
                              hipStream_t stream) {
    const void* x     = d_in[0];
    const void* E     = d_in[2];
    const void* W_fw  = d_in[3];
    const void* U_fw  = d_in[4];
    const void* b_fw  = d_in[5];
    const void* W_bw  = d_in[6];
    const void* U_bw  = d_in[7];
    const void* b_bw  = d_in[8];
    const void* W_m0  = d_in[9];
    const void* U_m0  = d_in[10];
    const void* b_m0  = d_in[11];
    const void* W_m1  = d_in[12];
    const void* U_m1  = d_in[13];
    const void* b_m1  = d_in[14];
    const void* W_top = d_in[15];
    const void* U_top = d_in[16];
    const void* b_top = d_in[17];

    float* ws = (float*)d_ws;
    float*    XPA = ws + OFF_XPA;
    float*    XPB = ws + OFF_XPB;
    float*    Y1  = XPB;
    float*    Y2  = XPB + 2097152;
    uint16_t* WTL = (uint16_t*)(XPB + 4194304);
    float*    YBI = ws + OFF_YBI;
    uint16_t* WTE = (uint16_t*)YBI;
    uint16_t* WTEb = WTE + 786432;
    int*      flags = (int*)(ws + OFF_FLG);
    int*      bar   = (int*)(ws + OFF_BAR);
    int*      el    = (int*)(ws + OFF_EL);
    uint16_t* hb    = (uint16_t*)(ws + OFF_H);

    // zero flags + barrier epochs + election counters
    hipMemsetAsync((char*)d_ws + (size_t)OFF_FLG*4, 0,
                   (size_t)(OFF_H - OFF_FLG)*4, stream);
    detect_dtypes<<<1, 64, 0, stream>>>(U_fw, x, flags);

    const dim3 b256(256);
    const dim3 gT512(16, 48), gT1024(32, 48);
    const dim3 gG2(24, 64, 2), gG1(24, 64, 1);

    // --- biGRU ---
    transpose_w<<<gT512, b256, 0, stream>>>(W_fw, WTE, 512, flags);
    transpose_w<<<gT512, b256, 0, stream>>>(W_bw, WTEb, 512, flags);
    gemm_mfma<<<gG2, b256, 0, stream>>>(nullptr, 0, x, E,
                                        WTE, b_fw, XPA,
                                        WTEb, b_bw, XPB, 512, flags);
    gru_mfma<<<256, 384, 0, stream>>>(XPA, U_fw, b_fw,
                                      XPB, U_bw, b_bw,
                                      x, YBI, 1024, nullptr, hb, bar, 0,
                                      el, 2, flags);
    // --- m0 (K=1024) ---
    transpose_w<<<gT1024, b256, 0, stream>>>(W_m0, WTL, 1024, flags);
    gemm_mfma<<<gG1, b256, 0, stream>>>(YBI, 1024, nullptr, nullptr,
                                        WTL, b_m0, XPA,
                                        nullptr, nullptr, nullptr, 1024, flags);
    hipMemsetAsync(el, 0, 64, stream);
    gru_mfma<<<256, 384, 0, stream>>>(XPA, U_m0, b_m0,
                                      nullptr, nullptr, nullptr,
                                      x, Y1, 512, nullptr, hb, bar, 2,
                                      el, 1, flags);
    // --- m1 ---
    transpose_w<<<gT512, b256, 0, stream>>>(W_m1, WTL, 512, flags);
    gemm_mfma<<<gG1, b256, 0, stream>>>(Y1, 512, nullptr, nullptr,
                                        WTL, b_m1, XPA,
                                        nullptr, nullptr, nullptr, 512, flags);
    hipMemsetAsync(el, 0, 64, stream);
    gru_mfma<<<256, 384, 0, stream>>>(XPA, U_m1, b_m1,
                                      nullptr, nullptr, nullptr,
                                      x, Y2, 512, nullptr, hb, bar, 3,
                                      el, 1, flags);
    // --- top ---
    transpose_w<<<gT512, b256, 0, stream>>>(W_top, WTL, 512, flags);
    gemm_mfma<<<gG1, b256, 0, stream>>>(Y2, 512, nullptr, nullptr,
                                        WTL, b_top, XPA,
                                        nullptr, nullptr, nullptr, 512, flags);
    hipMemsetAsync(el, 0, 64, stream);
    gru_mfma<<<256, 384, 0, stream>>>(XPA, U_top, b_top,
                                      nullptr, nullptr, nullptr,
                                      x, nullptr, 0, d_out, hb, bar, 4,
                                      el, 1, flags);
}